// Round 7
// baseline (495.854 us; speedup 1.0000x reference)
//
#include <hip/hip_runtime.h>
#include <stdint.h>

#define B_DIM 8
#define T_DIM 1024
#define C_DIM 2048
#define M_DIM (B_DIM * T_DIM)   // 8192 rows = B*T
#define SEG   64                // segments for wkv scan (R6: 32 -> 64)
#define SEGL  (T_DIM / SEG)     // 16 steps per segment

typedef __bf16 bf16x8 __attribute__((ext_vector_type(8)));
typedef __bf16 bf16x4 __attribute__((ext_vector_type(4)));
typedef float  f32x4  __attribute__((ext_vector_type(4)));

// ---------------------------------------------------------------------------
// async global -> LDS, 16 bytes per lane (global_load_lds_dwordx4).
// ---------------------------------------------------------------------------
__device__ __forceinline__ void gld_lds16(const void* g, void* l) {
    __builtin_amdgcn_global_load_lds((__attribute__((address_space(1))) void*)g,
                                     (__attribute__((address_space(3))) void*)l,
                                     16, 0, 0);
}

// ---------------------------------------------------------------------------
// Downcast the 4 weight matrices fp32 -> bf16.  8 elems/thread, 16-B stores.
// grid (C*C/2048, 4) x 256.
// ---------------------------------------------------------------------------
__global__ __launch_bounds__(256) void cast_w_kernel(
    const float* __restrict__ w0, const float* __restrict__ w1,
    const float* __restrict__ w2, const float* __restrict__ w3,
    __bf16* __restrict__ dst) {
    const float* srcs[4] = {w0, w1, w2, w3};
    const float* s = srcs[blockIdx.y];
    __bf16* d = dst + (size_t)blockIdx.y * (size_t)C_DIM * C_DIM;
    const size_t i = ((size_t)blockIdx.x * 256 + threadIdx.x) * 8;
    f32x4 v0 = *(const f32x4*)(s + i);
    f32x4 v1 = *(const f32x4*)(s + i + 4);
    bf16x8 o;
#pragma unroll
    for (int j = 0; j < 4; ++j) { o[j] = (__bf16)v0[j]; o[j + 4] = (__bf16)v1[j]; }
    *(bf16x8*)(d + i) = o;
}

// ---------------------------------------------------------------------------
// Time-shift mixing: xk/xv/xr = x*m + shift(x)*(1-m).  fp32 in, bf16 out.
// 8 elems/thread; all three outputs stored as bf16x8 (16 B).
// ---------------------------------------------------------------------------
__global__ __launch_bounds__(256) void mix4_kernel(
    const float* __restrict__ x,
    const float* __restrict__ mk, const float* __restrict__ mv,
    const float* __restrict__ mr,
    __bf16* __restrict__ xk, __bf16* __restrict__ xv, __bf16* __restrict__ xr) {
    const size_t idx = ((size_t)blockIdx.x * 256 + threadIdx.x) * 8;
    const int c = (int)(idx & (C_DIM - 1));
    const int t = (int)((idx >> 11) & (T_DIM - 1));   // C_DIM == 2^11

    f32x4 xc[2], sh[2] = {{0.f,0.f,0.f,0.f},{0.f,0.f,0.f,0.f}};
    xc[0] = *(const f32x4*)(x + idx);
    xc[1] = *(const f32x4*)(x + idx + 4);
    if (t != 0) {
        sh[0] = *(const f32x4*)(x + idx - C_DIM);
        sh[1] = *(const f32x4*)(x + idx - C_DIM + 4);
    }
    f32x4 k4[2], v4[2], r4[2];
    k4[0] = *(const f32x4*)(mk + c); k4[1] = *(const f32x4*)(mk + c + 4);
    v4[0] = *(const f32x4*)(mv + c); v4[1] = *(const f32x4*)(mv + c + 4);
    r4[0] = *(const f32x4*)(mr + c); r4[1] = *(const f32x4*)(mr + c + 4);

    bf16x8 ok, ov, orr;
#pragma unroll
    for (int h = 0; h < 2; ++h)
#pragma unroll
        for (int j = 0; j < 4; ++j) {
            float xx = xc[h][j], ss = sh[h][j];
            ok[h * 4 + j]  = (__bf16)(xx * k4[h][j] + ss * (1.f - k4[h][j]));
            ov[h * 4 + j]  = (__bf16)(xx * v4[h][j] + ss * (1.f - v4[h][j]));
            orr[h * 4 + j] = (__bf16)(xx * r4[h][j] + ss * (1.f - r4[h][j]));
        }
    *(bf16x8*)(xk + idx) = ok;
    *(bf16x8*)(xv + idx) = ov;
    *(bf16x8*)(xr + idx) = orr;
}

// ---------------------------------------------------------------------------
// 256x256 bf16 GEMM, B^T input:  Cout[m][n] = sum_k A[m][k] * W[n][k]
// R5 kernel FROZEN (best measured: 71.8-74.6 us, FETCH 49 MB, 0 conflicts).
// In-wave pipelined supertile schedule + m-banded XCD mapping.
// ---------------------------------------------------------------------------
#define LGKM(N)  do { asm volatile("s_waitcnt lgkmcnt(" #N ")" ::: "memory"); \
                      __builtin_amdgcn_sched_barrier(0); } while (0)
#define VM0()    asm volatile("s_waitcnt vmcnt(0)" ::: "memory")

#define MF1(mi, jj, AV, BV) \
    acc[mi][jj] = __builtin_amdgcn_mfma_f32_16x16x32_bf16(AV, BV, acc[mi][jj], 0, 0, 0)

#define MFMA16(MB, AA, BB)                                                        \
    __builtin_amdgcn_s_setprio(1);                                                \
    MF1(MB+0,0,AA[0],BB[0]); MF1(MB+0,1,AA[0],BB[1]);                             \
    MF1(MB+0,2,AA[0],BB[2]); MF1(MB+0,3,AA[0],BB[3]);                             \
    MF1(MB+1,0,AA[1],BB[0]); MF1(MB+1,1,AA[1],BB[1]);                             \
    MF1(MB+1,2,AA[1],BB[2]); MF1(MB+1,3,AA[1],BB[3]);                             \
    MF1(MB+2,0,AA[2],BB[0]); MF1(MB+2,1,AA[2],BB[1]);                             \
    MF1(MB+2,2,AA[2],BB[2]); MF1(MB+2,3,AA[2],BB[3]);                             \
    MF1(MB+3,0,AA[3],BB[0]); MF1(MB+3,1,AA[3],BB[1]);                             \
    MF1(MB+3,2,AA[3],BB[2]); MF1(MB+3,3,AA[3],BB[3]);                             \
    __builtin_amdgcn_s_setprio(0)

// stage one 64-K supertile (A and B, 256 rows x 64 k each): 8 gld_lds/thread.
#define STAGE8(KOF, BOE)                                                          \
    do {                                                                          \
        gld_lds16(Ag + (KOF),                       lA + (BOE));                  \
        gld_lds16(Bg + (KOF),                       lB + (BOE));                  \
        gld_lds16(Ag + (KOF) + (size_t)64*C_DIM,    lA + (BOE) + 4096);           \
        gld_lds16(Bg + (KOF) + (size_t)64*C_DIM,    lB + (BOE) + 4096);           \
        gld_lds16(Ag + (KOF) + (size_t)128*C_DIM,   lA + (BOE) + 8192);           \
        gld_lds16(Bg + (KOF) + (size_t)128*C_DIM,   lB + (BOE) + 8192);           \
        gld_lds16(Ag + (KOF) + (size_t)192*C_DIM,   lA + (BOE) + 12288);          \
        gld_lds16(Bg + (KOF) + (size_t)192*C_DIM,   lB + (BOE) + 12288);          \
    } while (0)

template <bool OUTF32>
__global__ __launch_bounds__(512, 2) void gemm256_bt(
    const __bf16* __restrict__ A, const __bf16* __restrict__ W,
    void* __restrict__ Cout) {
    __shared__ __align__(16) __bf16 sA[2 * 16384];   // 64 KB: 2 x [256][64]
    __shared__ __align__(16) __bf16 sB[2 * 16384];   // 64 KB

    const int tid  = threadIdx.x;
    const int lane = tid & 63;
    const int wave = tid >> 6;
    const int wr   = wave >> 2;        // 0..1 -> m offset wr*128
    const int wc   = wave & 3;         // 0..3 -> n offset wc*64

    // m-banded XCD mapping (bijective): xcd = bid&7 owns m_blks {4x..4x+3}
    // across all 8 n_blks -> per-XCD L2 footprint 4 MB A + 8 MB W.
    const int bid = blockIdx.x;
    const int xcd = bid & 7;
    const int loc = bid >> 3;          // 0..31
    const int m_blk = xcd * 4 + (loc & 3);
    const int n_blk = loc >> 2;        // 0..7
    const int row0 = m_blk * 256;
    const int col0 = n_blk * 256;

    // Staging source (inverse-swizzled global k-group so LDS DMA is linear):
    // linear LDS slot (row r = tid>>3, slot s' = tid&7) holds k-group
    // g = s' ^ (r&7).  Issue i advances rows by 64 (swizzle-invariant).
    const int srow = tid >> 3;
    const int sg   = (tid & 7) ^ (srow & 7);
    const __bf16* Ag = A + (size_t)(row0 + srow) * C_DIM + sg * 8;
    const __bf16* Bg = W + (size_t)(col0 + srow) * C_DIM + sg * 8;
    __bf16* lA = sA + wave * 512;      // + buf*16384 + issue*4096 (elements)
    __bf16* lB = sB + wave * 512;

    // Fragment read bases (elements).  Lane (row = R0 + l15, q = lane>>4)
    // reads k-group g = 4*ks + q at slot s' = g ^ (l15&7):
    //   elem = row*64 + s'*8;  ks=1 flips bit2 of s' -> XOR 32 elements.
    const int l15 = lane & 15;
    const int q   = lane >> 4;
    const int sw0 = (q ^ (l15 & 7)) * 8;
    const int aE0 = wr * 8192 + l15 * 64 + sw0;
    const int aE1 = aE0 ^ 32;
    const int bE0 = wc * 4096 + l15 * 64 + sw0;
    const int bE1 = bE0 ^ 32;

    f32x4  acc[8][4] = {};
    bf16x8 a0[4], a1[4], b0f[4], b1f[4];

    // ---- prologue: stage supertile 0 into buf0; preload phase-1 fragments.
    STAGE8(0, 0);
    VM0();
    __builtin_amdgcn_s_barrier();
#pragma unroll
    for (int i = 0; i < 4; ++i) a0[i]  = *(const bf16x8*)(sA + aE0 + i * 1024);
#pragma unroll
    for (int j = 0; j < 4; ++j) b0f[j] = *(const bf16x8*)(sB + bE0 + j * 1024);

    // ---- main loop: supertiles 0..30 (31 iters); supertile 31 peeled.
#pragma unroll 1
    for (int s = 0; s < 31; ++s) {
        const int boe  = (s & 1) << 14;      // current buf (elements)
        const int boe1 = boe ^ 16384;        // next buf

        // ph1 (mh0,ks0): prefetch a1 = A(mh1,ks0); stage s+1; MFMA.
#pragma unroll
        for (int i = 0; i < 4; ++i)
            a1[i] = *(const bf16x8*)(sA + boe + aE0 + 4096 + i * 1024);
        STAGE8((s + 1) * 64, boe1);
        LGKM(4);
        MFMA16(0, a0, b0f);

        // ph2 (mh1,ks0): prefetch a0 = A(mh0,ks1), b1f = B(ks1); MFMA.
#pragma unroll
        for (int i = 0; i < 4; ++i)
            a0[i]  = *(const bf16x8*)(sA + boe + aE1 + i * 1024);
#pragma unroll
        for (int j = 0; j < 4; ++j)
            b1f[j] = *(const bf16x8*)(sB + boe + bE1 + j * 1024);
        LGKM(8);
        MFMA16(4, a1, b0f);

        // ph3 (mh0,ks1): prefetch a1 = A(mh1,ks1); drain DMA; MFMA; mid-bar.
#pragma unroll
        for (int i = 0; i < 4; ++i)
            a1[i] = *(const bf16x8*)(sA + boe + aE1 + 4096 + i * 1024);
        VM0();
        LGKM(4);
        MFMA16(0, a0, b1f);
        __builtin_amdgcn_s_barrier();

        // ph4 (mh1,ks1): prefetch next supertile's ph1 frags from buf1; MFMA.
#pragma unroll
        for (int i = 0; i < 4; ++i)
            a0[i]  = *(const bf16x8*)(sA + boe1 + aE0 + i * 1024);
#pragma unroll
        for (int j = 0; j < 4; ++j)
            b0f[j] = *(const bf16x8*)(sB + boe1 + bE0 + j * 1024);
        LGKM(8);
        MFMA16(4, a1, b1f);
        __builtin_amdgcn_s_barrier();
    }

    // ---- peeled tail: supertile 31 (buf1), no staging, no barriers.
    {
        const int boe = 16384;
#pragma unroll
        for (int i = 0; i < 4; ++i)
            a1[i] = *(const bf16x8*)(sA + boe + aE0 + 4096 + i * 1024);
        LGKM(4);
        MFMA16(0, a0, b0f);
#pragma unroll
        for (int i = 0; i < 4; ++i)
            a0[i]  = *(const bf16x8*)(sA + boe + aE1 + i * 1024);
#pragma unroll
        for (int j = 0; j < 4; ++j)
            b1f[j] = *(const bf16x8*)(sB + boe + bE1 + j * 1024);
        LGKM(8);
        MFMA16(4, a1, b0f);
#pragma unroll
        for (int i = 0; i < 4; ++i)
            a1[i] = *(const bf16x8*)(sA + boe + aE1 + 4096 + i * 1024);
        LGKM(4);
        MFMA16(0, a0, b1f);
        LGKM(0);
        MFMA16(4, a1, b1f);
    }

    // Epilogue: D row = (lane>>4)*4 + reg, col = lane&15 (m89-verified).
    const int crow = (lane >> 4) * 4;
#pragma unroll
    for (int mf = 0; mf < 8; ++mf)
#pragma unroll
        for (int jf = 0; jf < 4; ++jf)
#pragma unroll
            for (int r = 0; r < 4; ++r) {
                const int row = row0 + wr * 128 + mf * 16 + crow + r;
                const int col = col0 + wc * 64 + jf * 16 + l15;
                if constexpr (OUTF32) {
                    ((float*)Cout)[(size_t)row * C_DIM + col] = acc[mf][jf][r];
                } else {
                    ((__bf16*)Cout)[(size_t)row * C_DIM + col] = (__bf16)acc[mf][jf][r];
                }
            }
}

// ---------------------------------------------------------------------------
// WKV segmented scan, R6: 16-B loads (bf16x8), 8 channels/thread, SEG=64.
// grid (1, B, SEG) = 512 blocks (2/CU), 256 threads.  Load batches fully
// unrolled ahead of the dependent exp-chain.  State [seg][b][c] fp32.
// ---------------------------------------------------------------------------
__global__ __launch_bounds__(256) void wkv_pass1(
    const __bf16* __restrict__ kbuf, const __bf16* __restrict__ vbuf,
    const float* __restrict__ td,
    float* __restrict__ st_num, float* __restrict__ st_den,
    float* __restrict__ st_m) {
    const int c0 = threadIdx.x * 8;                 // 256 thr x 8 = 2048 = C
    const int b = blockIdx.y;
    const int s = blockIdx.z;
    const size_t base = (size_t)b * T_DIM * C_DIM + (size_t)s * SEGL * C_DIM + c0;

    float w[8], num[8], den[8], mx[8];
    {
        f32x4 t0_ = *(const f32x4*)(td + c0);
        f32x4 t1_ = *(const f32x4*)(td + c0 + 4);
#pragma unroll
        for (int e = 0; e < 4; ++e) { w[e] = -__expf(t0_[e]); w[e+4] = -__expf(t1_[e]); }
#pragma unroll
        for (int e = 0; e < 8; ++e) { num[e] = 0.f; den[e] = 0.f; mx[e] = -1e38f; }
    }

    for (int t0 = 0; t0 < SEGL; t0 += 8) {          // SEGL=16 -> 2 iters
        bf16x8 kt[8], vt[8];
#pragma unroll
        for (int j = 0; j < 8; ++j) {
            const size_t idx = base + (size_t)(t0 + j) * C_DIM;
            kt[j] = *(const bf16x8*)(kbuf + idx);
            vt[j] = *(const bf16x8*)(vbuf + idx);
        }
#pragma unroll
        for (int j = 0; j < 8; ++j)
#pragma unroll
            for (int e = 0; e < 8; ++e) {
                float kk = (float)kt[j][e], vv = (float)vt[j][e];
                float ms  = fmaxf(mx[e] + w[e], kk);
                float e1s = __expf(mx[e] + w[e] - ms);
                float e2s = __expf(kk - ms);
                num[e] = e1s * num[e] + e2s * vv;
                den[e] = e1s * den[e] + e2s;
                mx[e]  = ms;
            }
    }
    const size_t sidx = (size_t)s * (B_DIM * C_DIM) + (size_t)b * C_DIM + c0;
    f32x4 o0, o1;
#pragma unroll
    for (int e = 0; e < 4; ++e) { o0[e] = num[e]; o1[e] = num[e+4]; }
    *(f32x4*)(st_num + sidx) = o0; *(f32x4*)(st_num + sidx + 4) = o1;
#pragma unroll
    for (int e = 0; e < 4; ++e) { o0[e] = den[e]; o1[e] = den[e+4]; }
    *(f32x4*)(st_den + sidx) = o0; *(f32x4*)(st_den + sidx + 4) = o1;
#pragma unroll
    for (int e = 0; e < 4; ++e) { o0[e] = mx[e]; o1[e] = mx[e+4]; }
    *(f32x4*)(st_m + sidx) = o0; *(f32x4*)(st_m + sidx + 4) = o1;
}

__global__ __launch_bounds__(256) void wkv_pass2(
    const float* __restrict__ td,
    float* __restrict__ st_num, float* __restrict__ st_den,
    float* __restrict__ st_m) {
    const int bc = blockIdx.x * 256 + threadIdx.x;   // b*C + c
    const int c  = bc & (C_DIM - 1);
    const float w = -__expf(td[c]);
    const float wL = w * SEGL;

    float num = 0.f, den = 0.f, mx = -1e38f;
    for (int s = 0; s < SEG; ++s) {
        const size_t sidx = (size_t)s * (B_DIM * C_DIM) + bc;
        float na = st_num[sidx], da = st_den[sidx], ma = st_m[sidx];
        // write incoming state for this segment (overwrite aggregate)
        st_num[sidx] = num; st_den[sidx] = den; st_m[sidx] = mx;
        // combine: state <- decay^L(state) + aggregate
        float md = mx + wL;
        float mc = fmaxf(md, ma);
        float e1 = __expf(md - mc);
        float e2 = __expf(ma - mc);
        num = e1 * num + e2 * na;
        den = e1 * den + e2 * da;
        mx  = mc;
    }
}

__global__ __launch_bounds__(256) void wkv_pass3(
    const __bf16* __restrict__ kbuf, const __bf16* __restrict__ vbuf,
    const __bf16* __restrict__ rbuf, const float* __restrict__ td,
    const float* __restrict__ tf,
    const float* __restrict__ st_num, const float* __restrict__ st_den,
    const float* __restrict__ st_m, __bf16* __restrict__ abuf) {
    const int c0 = threadIdx.x * 8;
    const int b = blockIdx.y;
    const int s = blockIdx.z;
    const size_t base = (size_t)b * T_DIM * C_DIM + (size_t)s * SEGL * C_DIM + c0;

    const size_t sidx = (size_t)s * (B_DIM * C_DIM) + (size_t)b * C_DIM + c0;
    float w[8], u[8], num[8], den[8], mx[8];
    {
        f32x4 t0_ = *(const f32x4*)(td + c0);
        f32x4 t1_ = *(const f32x4*)(td + c0 + 4);
        f32x4 u0_ = *(const f32x4*)(tf + c0);
        f32x4 u1_ = *(const f32x4*)(tf + c0 + 4);
        f32x4 n0 = *(const f32x4*)(st_num + sidx), n1 = *(const f32x4*)(st_num + sidx + 4);
        f32x4 d0 = *(const f32x4*)(st_den + sidx), d1 = *(const f32x4*)(st_den + sidx + 4);
        f32x4 m0 = *(const f32x4*)(st_m + sidx),   m1 = *(const f32x4*)(st_m + sidx + 4);
#pragma unroll
        for (int e = 0; e < 4; ++e) {
            w[e] = -__expf(t0_[e]); w[e+4] = -__expf(t1_[e]);
            u[e] = u0_[e];          u[e+4] = u1_[e];
            num[e] = n0[e]; num[e+4] = n1[e];
            den[e] = d0[e]; den[e+4] = d1[e];
            mx[e]  = m0[e]; mx[e+4]  = m1[e];
        }
    }

    for (int t0 = 0; t0 < SEGL; t0 += 4) {          // SEGL=16 -> 4 iters
        bf16x8 kt[4], vt[4], rt[4];
#pragma unroll
        for (int j = 0; j < 4; ++j) {
            const size_t idx = base + (size_t)(t0 + j) * C_DIM;
            kt[j] = *(const bf16x8*)(kbuf + idx);
            vt[j] = *(const bf16x8*)(vbuf + idx);
            rt[j] = *(const bf16x8*)(rbuf + idx);
        }
#pragma unroll
        for (int j = 0; j < 4; ++j) {
            bf16x8 o8;
#pragma unroll
            for (int e = 0; e < 8; ++e) {
                float kk = (float)kt[j][e], vv = (float)vt[j][e], rr = (float)rt[j][e];
                float mo  = fmaxf(mx[e], kk + u[e]);
                float e1  = __expf(mx[e] - mo);
                float e2  = __expf(kk + u[e] - mo);
                float out = (e1 * num[e] + e2 * vv) / (e1 * den[e] + e2);

                float ms  = fmaxf(mx[e] + w[e], kk);
                float e1s = __expf(mx[e] + w[e] - ms);
                float e2s = __expf(kk - ms);
                num[e] = e1s * num[e] + e2s * vv;
                den[e] = e1s * den[e] + e2s;
                mx[e]  = ms;

                float sr = 1.f / (1.f + __expf(-rr));
                o8[e] = (__bf16)(sr * out);
            }
            *(bf16x8*)(abuf + base + (size_t)(t0 + j) * C_DIM) = o8;
        }
    }
}

// ---------------------------------------------------------------------------
extern "C" void kernel_launch(void* const* d_in, const int* in_sizes, int n_in,
                              void* d_out, int out_size, void* d_ws, size_t ws_size,
                              hipStream_t stream) {
    (void)in_sizes; (void)n_in; (void)out_size; (void)ws_size;
    const float* x  = (const float*)d_in[0];
    const float* td = (const float*)d_in[1];
    const float* tf = (const float*)d_in[2];
    const float* mk = (const float*)d_in[3];
    const float* mv = (const float*)d_in[4];
    const float* mr = (const float*)d_in[5];
    const float* Wk = (const float*)d_in[6];
    const float* Wv = (const float*)d_in[7];
    const float* Wr = (const float*)d_in[8];
    const float* Wo = (const float*)d_in[9];
    float* out = (float*)d_out;

    const size_t WN = (size_t)C_DIM * C_DIM;    // 4,194,304
    const size_t n  = (size_t)M_DIM * C_DIM;    // 16,777,216

    // ws layout (bf16 elements): [Wk|Wv|Wr|Wo bf16][slot0][slot1][slot2][slot3]
    __bf16* Wb  = (__bf16*)d_ws;
    __bf16* Wkb = Wb;
    __bf16* Wvb = Wb + WN;
    __bf16* Wrb = Wb + 2 * WN;
    __bf16* Wob = Wb + 3 * WN;
    __bf16* xk  = Wb + 4 * WN;                  // slot 0
    __bf16* xv  = xk + n;                       // slot 1
    __bf16* xr  = xv + n;                       // slot 2
    __bf16* kb  = xr + n;                       // slot 3
    __bf16* vb  = xk;                           // reuse slot 0 (xk dead)
    __bf16* rb  = xv;                           // reuse slot 1 (xv dead)
    __bf16* ab  = xr;                           // reuse slot 2 (xr dead)

    // WKV state arrays (12.6 MB at SEG=64) live in the Wkb+Wvb region: both
    // are dead once the k- and v-GEMMs complete (p1 runs after), and cast_w
    // rewrites them at the start of every launch.  Wrb/Wob untouched.
    float* st_num = (float*)d_ws;
    float* st_den = st_num + (size_t)SEG * B_DIM * C_DIM;
    float* st_m   = st_den + (size_t)SEG * B_DIM * C_DIM;

    cast_w_kernel<<<dim3((unsigned)(WN / 8 / 256), 4), 256, 0, stream>>>(
        Wk, Wv, Wr, Wo, Wb);

    mix4_kernel<<<dim3((unsigned)(n / 8 / 256)), 256, 0, stream>>>(
        x, mk, mv, mr, xk, xv, xr);

    dim3 ggrid((M_DIM / 256) * (C_DIM / 256));  // 32 x 8 = 256 blocks (1/CU)
    gemm256_bt<false><<<ggrid, 512, 0, stream>>>(xk, Wkb, kb);
    gemm256_bt<false><<<ggrid, 512, 0, stream>>>(xv, Wvb, vb);
    gemm256_bt<false><<<ggrid, 512, 0, stream>>>(xr, Wrb, rb);

    dim3 wgrid(1, B_DIM, SEG);                  // 1 x 8 x 64 = 512 blocks
    wkv_pass1<<<wgrid, 256, 0, stream>>>(kb, vb, td, st_num, st_den, st_m);
    wkv_pass2<<<dim3(B_DIM * C_DIM / 256), 256, 0, stream>>>(
        td, st_num, st_den, st_m);
    wkv_pass3<<<wgrid, 256, 0, stream>>>(kb, vb, rb, td, tf,
                                         st_num, st_den, st_m, ab);

    gemm256_bt<true><<<ggrid, 512, 0, stream>>>(ab, Wob, out);
}